// Round 10
// baseline (178.892 us; speedup 1.0000x reference)
//
#include <hip/hip_runtime.h>
#include <hip/hip_bf16.h>

typedef __bf16 bf16x8 __attribute__((ext_vector_type(8)));
typedef __bf16 bf16x4 __attribute__((ext_vector_type(4)));
typedef float f32x4 __attribute__((ext_vector_type(4)));

#define NROW 3072
#define NF 512            // IN_F == H*D == 512
#define NH 8
#define ND 64

// Order-preserving float<->uint key for atomicMax over signed floats.
__device__ __forceinline__ unsigned enc_key(float f) {
    unsigned u = __float_as_uint(f);
    return (f < 0.f) ? ~u : (u | 0x80000000u);
}
__device__ __forceinline__ float dec_key(unsigned k) {
    unsigned u = (k & 0x80000000u) ? (k ^ 0x80000000u) : ~k;
    return __uint_as_float(u);
}

// ---------------------------------------------------------------------------
// Kernel 0: convert x AND W fp32 -> bf16 (one dispatch); init maxkey.
// 458752 float4 slots: first 393216 are x, rest W. Grid 1792 x 256.
// ---------------------------------------------------------------------------
__global__ __launch_bounds__(256) void k_conv(const float* __restrict__ x,
                                              const float* __restrict__ W,
                                              __bf16* __restrict__ xb,
                                              __bf16* __restrict__ Wb,
                                              unsigned* __restrict__ maxkey) {
    if (blockIdx.x == 0 && threadIdx.x < NH) maxkey[threadIdx.x] = 0u;
    int k = blockIdx.x * 256 + threadIdx.x;
    const float4* s; __bf16* d;
    if (k < 393216) { s = (const float4*)x; d = xb; }
    else { k -= 393216;  s = (const float4*)W; d = Wb; }
    float4 v = s[k];
    bf16x4 o = { (__bf16)v.x, (__bf16)v.y, (__bf16)v.z, (__bf16)v.w };
    *reinterpret_cast<bf16x4*>(d + k * 4) = o;
}

// ---------------------------------------------------------------------------
// Kernel 1: pack (adj>0 || j==i) into bitmask bits[3072][96] u32 (1.18 MB).
// ---------------------------------------------------------------------------
__global__ __launch_bounds__(256) void k_bitpack(const int* __restrict__ adj,
                                                 unsigned long long* __restrict__ bits64) {
    int i = blockIdx.x;
    int wave = threadIdx.x >> 6, lane = threadIdx.x & 63;
    const int* row = adj + i * NROW;
#pragma unroll
    for (int it = 0; it < 12; ++it) {
        int base = wave * 768 + it * 64;
        int j = base + lane;
        bool pred = (row[j] > 0) || (j == i);
        unsigned long long bal = __ballot(pred);
        if (lane == 0) bits64[i * 48 + (base >> 6)] = bal;
    }
}

// ---------------------------------------------------------------------------
// Kernel 2: h = x @ W^T (both bf16); write hT only (per-head d-major) via
// LDS transpose. 1536 blocks x 4 wave-tiles (16x16).
// ---------------------------------------------------------------------------
__global__ __launch_bounds__(256) void k_gemm(const __bf16* __restrict__ xb,
                                              const __bf16* __restrict__ Wb,
                                              __bf16* __restrict__ hT) {
    __shared__ __bf16 tile[4][16][17];
    int wave = threadIdx.x >> 6;
    int lane = threadIdx.x & 63;
    int t = blockIdx.x * 4 + wave;          // 6144 tiles: 192 i-tiles x 32 o-tiles
    int i0 = (t >> 5) << 4;
    int o0 = (t & 31) << 4;
    int fr = lane & 15;
    int quad = lane >> 4;

    const bf16x8* xa = reinterpret_cast<const bf16x8*>(xb + (i0 + fr) * NF + quad * 8);
    const bf16x8* wp = reinterpret_cast<const bf16x8*>(Wb + (o0 + fr) * NF + quad * 8);

    f32x4 acc = {0.f, 0.f, 0.f, 0.f};
#pragma unroll
    for (int k = 0; k < 16; ++k) {
        bf16x8 a = xa[k * 4];
        bf16x8 b = wp[k * 4];
        acc = __builtin_amdgcn_mfma_f32_16x16x32_bf16(a, b, acc, 0, 0, 0);
    }
#pragma unroll
    for (int r = 0; r < 4; ++r)
        tile[wave][quad * 4 + r][fr] = (__bf16)acc[r];
    __syncthreads();
    int orow = lane >> 2;
    int li = (lane & 3) * 4;
    bf16x4 o4 = { tile[wave][li][orow], tile[wave][li + 1][orow],
                  tile[wave][li + 2][orow], tile[wave][li + 3][orow] };
    *reinterpret_cast<bf16x4*>(hT + (o0 + orow) * NROW + i0 + li) = o4;
}

// ---------------------------------------------------------------------------
// Kernel 3: e_srcT[h][i], e_dstT[h][i] from hT (coalesced row reads) + fused
// per-head global max. Grid dim3(12, 8).
// ---------------------------------------------------------------------------
__global__ __launch_bounds__(256) void k_edgesT(const __bf16* __restrict__ hT,
                                                const float* __restrict__ a_src,
                                                const float* __restrict__ a_dst,
                                                float* __restrict__ e_srcT,
                                                float* __restrict__ e_dstT,
                                                unsigned* __restrict__ maxkey) {
    int hh = blockIdx.y;
    int i = blockIdx.x * 256 + threadIdx.x;
    float ps = 0.f, pd = 0.f;
#pragma unroll
    for (int d = 0; d < ND; ++d) {
        float hv = (float)hT[(hh * ND + d) * NROW + i];
        ps += hv * a_src[hh * ND + d];
        pd += hv * a_dst[hh * ND + d];
    }
    e_srcT[hh * NROW + i] = ps;
    e_dstT[hh * NROW + i] = pd;
    float mx = pd;
#pragma unroll
    for (int off = 1; off < 64; off <<= 1) mx = fmaxf(mx, __shfl_xor(mx, off, 64));
    if ((threadIdx.x & 63) == 0) atomicMax(&maxkey[hh], enc_key(mx));
}

// ---------------------------------------------------------------------------
// Kernel 4: masked softmax-PV. JCV=2; block = 64 i-rows x one head x one
// j-chunk (1536 j). 8 waves: iw = w&3 (16-row group), dw = w>>2 (d-half of
// 32). LDS-staged 64-j hT chunks (double-buffered, frag-ordered,
// conflict-free), shared by all 8 waves. den via MFMA-ones (dw==0 only
// stores). Factored exp: p = mask * (P_j>T_i ? A_i*P_j : C_i*Q_j).
// Grid: 48 i-blocks x 2 jc x 8 heads = 768 blocks, 512 thr, 28 KB LDS.
// ---------------------------------------------------------------------------
__global__ __launch_bounds__(512) void k_attn(const unsigned* __restrict__ bits,
                                              const float* __restrict__ e_srcT,
                                              const float* __restrict__ e_dstT,
                                              const unsigned* __restrict__ maxkey,
                                              const __bf16* __restrict__ hT,
                                              float* __restrict__ num,
                                              float* __restrict__ den) {
    constexpr int JCHUNK = NROW / 2;         // 1536
    constexpr int NC = JCHUNK / 64;          // 24 chunks of 64 j
    __shared__ __align__(16) float2 lds_pq[JCHUNK];      // 12 KB
    __shared__ __align__(16) __bf16 hbuf[2][4096];       // 2 x 8 KB
    int b = blockIdx.x;
    int head = b & 7;
    int jc = (b >> 3) & 1;
    int i0 = (b >> 4) * 64;
    int jbase = jc * JCHUNK;
    int tid = threadIdx.x;
    int wave = tid >> 6, lane = tid & 63;
    int fr = lane & 15, quad = lane >> 4;
    int iw = wave & 3, dw = wave >> 2;

    float Mg = dec_key(maxkey[head]);
    // per-thread float2 fill: 8B/lane consecutive -> 2-way aliasing (free)
    for (int j = tid; j < JCHUNK; j += 512) {
        float t = e_dstT[head * NROW + jbase + j] - Mg;   // <= 0
        lds_pq[j] = make_float2(__expf(t), __expf(0.2f * t));
    }

    int irow = i0 + iw * 16 + fr;
    float u = e_srcT[head * NROW + irow] + Mg;
    float A = (u > 0.f) ? 1.f : __expf(0.8f * u);
    float C = (u > 0.f) ? __expf(-0.8f * u) : 1.f;
    float T = __expf(-u);
    const unsigned* brow = bits + irow * 96 + jc * (JCHUNK / 32);

    // staging: 512 slots of 8 bf16 (8 KB chunk); slot s = tid:
    // jh=s>>8, dt=(s>>6)&3, sfr=s&15, sq=(s>>4)&3;
    // src = hT[(head*64 + dt*16 + sfr)*NROW + jbase + jh*32 + sq*8 + k*64]
    const __bf16* gsrc = hT + (head * ND + ((tid >> 6) & 3) * 16 + (tid & 15)) * NROW
                            + jbase + (tid >> 8) * 32 + ((tid >> 4) & 3) * 8;
    *reinterpret_cast<bf16x8*>(&hbuf[0][tid * 8]) = *reinterpret_cast<const bf16x8*>(gsrc);
    __syncthreads();

    const bf16x8 ones = { (__bf16)1.f, (__bf16)1.f, (__bf16)1.f, (__bf16)1.f,
                          (__bf16)1.f, (__bf16)1.f, (__bf16)1.f, (__bf16)1.f };
    f32x4 acc0 = {0,0,0,0}, acc1 = {0,0,0,0}, acc4 = {0,0,0,0};
    uint2 wm = *reinterpret_cast<const uint2*>(brow);

    for (int k = 0; k < NC; ++k) {
        bf16x8 st;
        uint2 wmn = wm;
        bool more = (k + 1 < NC);
        if (more) {
            st = *reinterpret_cast<const bf16x8*>(gsrc + (k + 1) * 64);
            wmn = *reinterpret_cast<const uint2*>(brow + (k + 1) * 2);
        }
        const __bf16* hb = &hbuf[k & 1][0];
#pragma unroll
        for (int jh = 0; jh < 2; ++jh) {
            int j0 = k * 64 + jh * 32;
            unsigned w = (jh ? wm.y : wm.x) >> (quad * 8);
            bf16x8 v0 = *reinterpret_cast<const bf16x8*>(hb + jh * 2048 + (dw * 2 + 0) * 512 + lane * 8);
            bf16x8 v1 = *reinterpret_cast<const bf16x8*>(hb + jh * 2048 + (dw * 2 + 1) * 512 + lane * 8);
            const float4* lp = reinterpret_cast<const float4*>(&lds_pq[j0 + quad * 8]);
            float4 q01 = lp[0], q23 = lp[1], q45 = lp[2], q67 = lp[3];
            float P[8] = {q01.x, q01.z, q23.x, q23.z, q45.x, q45.z, q67.x, q67.z};
            float Q[8] = {q01.y, q01.w, q23.y, q23.w, q45.y, q45.w, q67.y, q67.w};
            bf16x8 af;
#pragma unroll
            for (int t = 0; t < 8; ++t) {
                bool pos = P[t] > T;
                float p = (pos ? P[t] : Q[t]) * (pos ? A : C);
                af[t] = ((w >> t) & 1u) ? (__bf16)p : (__bf16)0.f;
            }
            acc0 = __builtin_amdgcn_mfma_f32_16x16x32_bf16(af, v0, acc0, 0, 0, 0);
            acc1 = __builtin_amdgcn_mfma_f32_16x16x32_bf16(af, v1, acc1, 0, 0, 0);
            acc4 = __builtin_amdgcn_mfma_f32_16x16x32_bf16(af, ones, acc4, 0, 0, 0);
        }
        if (more)
            *reinterpret_cast<bf16x8*>(&hbuf[(k + 1) & 1][tid * 8]) = st;
        wm = wmn;
        __syncthreads();
    }

    // den: acc4 rows hold sum_j p (replicated across cols); dw==0 stores.
    if (dw == 0 && fr == 0) {
#pragma unroll
        for (int r = 0; r < 4; ++r)
            den[(jc * NROW + i0 + iw * 16 + quad * 4 + r) * NH + head] = acc4[r];
    }
#pragma unroll
    for (int r = 0; r < 4; ++r) {
        int orow = quad * 4 + r;
        int ob = (jc * NROW + i0 + iw * 16 + orow) * NF + head * ND + dw * 32 + fr;
        num[ob +  0] = acc0[r];
        num[ob + 16] = acc1[r];
    }
}

// ---------------------------------------------------------------------------
// Kernel 5: out[i,c] = (num[0][i][c]+num[1][i][c]) / (den[0][i][h]+den[1][i][h])
// ---------------------------------------------------------------------------
__global__ __launch_bounds__(256) void k_reduce(const float* __restrict__ num,
                                                const float* __restrict__ den,
                                                float* __restrict__ out) {
    int idx = blockIdx.x * 256 + threadIdx.x;     // 0 .. NROW*NF
    int i = idx >> 9;
    int c = idx & 511;
    int head = c >> 6;
    float ns = num[i * NF + c] + num[(NROW + i) * NF + c];
    float ds = den[i * NH + head] + den[(NROW + i) * NH + head];
    out[idx] = ns / fmaxf(ds, 1e-30f);
}

// ---------------------------------------------------------------------------
extern "C" void kernel_launch(void* const* d_in, const int* in_sizes, int n_in,
                              void* d_out, int out_size, void* d_ws, size_t ws_size,
                              hipStream_t stream) {
    const float* x_raw  = (const float*)d_in[0];
    const int*   adj    = (const int*)d_in[1];
    const float* W_raw  = (const float*)d_in[2];
    const float* as_raw = (const float*)d_in[3];
    const float* ad_raw = (const float*)d_in[4];
    float* out = (float*)d_out;

    char* ws = (char*)d_ws;
    __bf16*   hT     = (__bf16*)(ws);                    // 3,145,728 B
    float*    e_srcT = (float*)(ws + 3145728);           //    98,304 B
    float*    e_dstT = (float*)(ws + 3244032);           //    98,304 B
    unsigned* maxkey = (unsigned*)(ws + 3342336);        //        64 B
    unsigned* bits   = (unsigned*)(ws + 3342400);        // 1,179,648 B
    __bf16*   xb     = (__bf16*)(ws + 4522048);          // 3,145,728 B
    __bf16*   Wb     = (__bf16*)(ws + 7667776);          //   524,288 B
    float*    num    = (float*)(ws + 8192064);           // 12,582,912 B
    float*    den    = (float*)(ws + 20774976);          //   196,608 B
    // total 20,971,584 B (< previously-verified 30.6 MB capacity)

    k_conv<<<1792, 256, 0, stream>>>(x_raw, W_raw, xb, Wb, maxkey);
    k_bitpack<<<NROW, 256, 0, stream>>>(adj, (unsigned long long*)bits);
    k_gemm<<<1536, 256, 0, stream>>>(xb, Wb, hT);
    k_edgesT<<<dim3(12, 8), 256, 0, stream>>>(hT, as_raw, ad_raw, e_srcT, e_dstT, maxkey);
    k_attn<<<48 * 2 * 8, 512, 0, stream>>>(bits, e_srcT, e_dstT, maxkey, hT, num, den);
    k_reduce<<<NROW * NF / 256, 256, 0, stream>>>(num, den, out);
}

// Round 12
// 163.333 us; speedup vs baseline: 1.0953x; 1.0953x over previous
//
#include <hip/hip_runtime.h>
#include <hip/hip_bf16.h>

typedef __bf16 bf16x8 __attribute__((ext_vector_type(8)));
typedef __bf16 bf16x4 __attribute__((ext_vector_type(4)));
typedef float f32x4 __attribute__((ext_vector_type(4)));

#define NROW 3072
#define NF 512            // IN_F == H*D == 512
#define NH 8
#define ND 64

// Order-preserving float<->uint key for atomicMax over signed floats.
__device__ __forceinline__ unsigned enc_key(float f) {
    unsigned u = __float_as_uint(f);
    return (f < 0.f) ? ~u : (u | 0x80000000u);
}
__device__ __forceinline__ float dec_key(unsigned k) {
    unsigned u = (k & 0x80000000u) ? (k ^ 0x80000000u) : ~k;
    return __uint_as_float(u);
}

// ---------------------------------------------------------------------------
// Kernel 0 (merged prep): blocks 0..1791 convert x,W fp32->bf16 (float4);
// blocks 1792..4863 bitpack (adj>0 || j==i) into bits[3072][96] (1.18 MB).
// ---------------------------------------------------------------------------
__global__ __launch_bounds__(256) void k_prep(const float* __restrict__ x,
                                              const float* __restrict__ W,
                                              const int* __restrict__ adj,
                                              __bf16* __restrict__ xb,
                                              __bf16* __restrict__ Wb,
                                              unsigned long long* __restrict__ bits64,
                                              unsigned* __restrict__ maxkey) {
    if (blockIdx.x == 0 && threadIdx.x < NH) maxkey[threadIdx.x] = 0u;
    if (blockIdx.x < 1792) {
        int k = blockIdx.x * 256 + threadIdx.x;
        const float4* s; __bf16* d;
        if (k < 393216) { s = (const float4*)x; d = xb; }
        else { k -= 393216;  s = (const float4*)W; d = Wb; }
        float4 v = s[k];
        bf16x4 o = { (__bf16)v.x, (__bf16)v.y, (__bf16)v.z, (__bf16)v.w };
        *reinterpret_cast<bf16x4*>(d + k * 4) = o;
    } else {
        int i = blockIdx.x - 1792;
        int wave = threadIdx.x >> 6, lane = threadIdx.x & 63;
        const int* row = adj + i * NROW;
#pragma unroll
        for (int it = 0; it < 12; ++it) {
            int base = wave * 768 + it * 64;
            int j = base + lane;
            bool pred = (row[j] > 0) || (j == i);
            unsigned long long bal = __ballot(pred);
            if (lane == 0) bits64[i * 48 + (base >> 6)] = bal;
        }
    }
}

// ---------------------------------------------------------------------------
// Kernel 1: h = x @ W^T (both bf16); write hT only (per-head d-major) via
// LDS transpose. 1536 blocks x 4 wave-tiles (16x16).
// ---------------------------------------------------------------------------
__global__ __launch_bounds__(256) void k_gemm(const __bf16* __restrict__ xb,
                                              const __bf16* __restrict__ Wb,
                                              __bf16* __restrict__ hT) {
    __shared__ __bf16 tile[4][16][17];
    int wave = threadIdx.x >> 6;
    int lane = threadIdx.x & 63;
    int t = blockIdx.x * 4 + wave;          // 6144 tiles: 192 i-tiles x 32 o-tiles
    int i0 = (t >> 5) << 4;
    int o0 = (t & 31) << 4;
    int fr = lane & 15;
    int quad = lane >> 4;

    const bf16x8* xa = reinterpret_cast<const bf16x8*>(xb + (i0 + fr) * NF + quad * 8);
    const bf16x8* wp = reinterpret_cast<const bf16x8*>(Wb + (o0 + fr) * NF + quad * 8);

    f32x4 acc = {0.f, 0.f, 0.f, 0.f};
#pragma unroll
    for (int k = 0; k < 16; ++k) {
        bf16x8 a = xa[k * 4];
        bf16x8 b = wp[k * 4];
        acc = __builtin_amdgcn_mfma_f32_16x16x32_bf16(a, b, acc, 0, 0, 0);
    }
#pragma unroll
    for (int r = 0; r < 4; ++r)
        tile[wave][quad * 4 + r][fr] = (__bf16)acc[r];
    __syncthreads();
    int orow = lane >> 2;
    int li = (lane & 3) * 4;
    bf16x4 o4 = { tile[wave][li][orow], tile[wave][li + 1][orow],
                  tile[wave][li + 2][orow], tile[wave][li + 3][orow] };
    *reinterpret_cast<bf16x4*>(hT + (o0 + orow) * NROW + i0 + li) = o4;
}

// ---------------------------------------------------------------------------
// Kernel 2: e_srcT[h][i], e_dstT[h][i] from hT (coalesced row reads) + fused
// per-head global max. Grid dim3(12, 8).
// ---------------------------------------------------------------------------
__global__ __launch_bounds__(256) void k_edgesT(const __bf16* __restrict__ hT,
                                                const float* __restrict__ a_src,
                                                const float* __restrict__ a_dst,
                                                float* __restrict__ e_srcT,
                                                float* __restrict__ e_dstT,
                                                unsigned* __restrict__ maxkey) {
    int hh = blockIdx.y;
    int i = blockIdx.x * 256 + threadIdx.x;
    float ps = 0.f, pd = 0.f;
#pragma unroll
    for (int d = 0; d < ND; ++d) {
        float hv = (float)hT[(hh * ND + d) * NROW + i];
        ps += hv * a_src[hh * ND + d];
        pd += hv * a_dst[hh * ND + d];
    }
    e_srcT[hh * NROW + i] = ps;
    e_dstT[hh * NROW + i] = pd;
    float mx = pd;
#pragma unroll
    for (int off = 1; off < 64; off <<= 1) mx = fmaxf(mx, __shfl_xor(mx, off, 64));
    if ((threadIdx.x & 63) == 0) atomicMax(&maxkey[hh], enc_key(mx));
}

// ---------------------------------------------------------------------------
// Kernel 3: masked softmax-PV (the proven R8 shape). 128 i-rows per block
// (8 waves x 16 rows, each wave FULL d=64 -> p computed once); LDS-staged
// 64-j hT chunks (double-buffered, frag-ordered, conflict-free) shared by
// all 8 waves. den via MFMA-ones (acc4). Factored exp:
//   p = mask * (P_j>T_i ? A_i*P_j : C_i*Q_j).
// Grid: 24 i-blocks x 4 jc x 8 heads = 768 blocks, 512 thr, 22 KB LDS.
// ---------------------------------------------------------------------------
template <int JCV>
__global__ __launch_bounds__(512) void k_attn(const unsigned* __restrict__ bits,
                                              const float* __restrict__ e_srcT,
                                              const float* __restrict__ e_dstT,
                                              const unsigned* __restrict__ maxkey,
                                              const __bf16* __restrict__ hT,
                                              float* __restrict__ num,
                                              float* __restrict__ den) {
    constexpr int JCHUNK = NROW / JCV;       // 768 (JCV=4)
    constexpr int NC = JCHUNK / 64;          // 12 chunks of 64 j
    __shared__ __align__(16) float2 lds_pq[JCHUNK];      // 6 KB
    __shared__ __align__(16) __bf16 hbuf[2][4096];       // 2 x 8 KB
    int b = blockIdx.x;
    int head = b & 7;
    int jc = (b >> 3) & (JCV - 1);
    int i0 = ((b >> 3) / JCV) * 128;
    int jbase = jc * JCHUNK;
    int tid = threadIdx.x;
    int wave = tid >> 6, lane = tid & 63;
    int fr = lane & 15, quad = lane >> 4;

    float Mg = dec_key(maxkey[head]);
    for (int j = tid; j < JCHUNK; j += 512) {
        float t = e_dstT[head * NROW + jbase + j] - Mg;   // <= 0
        lds_pq[j] = make_float2(__expf(t), __expf(0.2f * t));
    }

    int irow = i0 + wave * 16 + fr;
    float u = e_srcT[head * NROW + irow] + Mg;
    float A = (u > 0.f) ? 1.f : __expf(0.8f * u);
    float C = (u > 0.f) ? __expf(-0.8f * u) : 1.f;
    float T = __expf(-u);
    const unsigned* brow = bits + irow * 96 + jc * (JCHUNK / 32);

    // staging: 512 slots of 8 bf16; slot s = tid:
    // jh=s>>8, dt=(s>>6)&3, sfr=s&15, sq=(s>>4)&3;
    // src = hT[(head*64 + dt*16 + sfr)*NROW + jbase + jh*32 + sq*8 + k*64]
    const __bf16* gsrc = hT + (head * ND + ((tid >> 6) & 3) * 16 + (tid & 15)) * NROW
                            + jbase + (tid >> 8) * 32 + ((tid >> 4) & 3) * 8;
    *reinterpret_cast<bf16x8*>(&hbuf[0][tid * 8]) = *reinterpret_cast<const bf16x8*>(gsrc);
    __syncthreads();

    const bf16x8 ones = { (__bf16)1.f, (__bf16)1.f, (__bf16)1.f, (__bf16)1.f,
                          (__bf16)1.f, (__bf16)1.f, (__bf16)1.f, (__bf16)1.f };
    f32x4 acc0 = {0,0,0,0}, acc1 = {0,0,0,0}, acc2 = {0,0,0,0}, acc3 = {0,0,0,0};
    f32x4 acc4 = {0,0,0,0};
    uint2 wm = *reinterpret_cast<const uint2*>(brow);

    for (int k = 0; k < NC; ++k) {
        bf16x8 st;
        uint2 wmn = wm;
        bool more = (k + 1 < NC);
        if (more) {
            st = *reinterpret_cast<const bf16x8*>(gsrc + (k + 1) * 64);
            wmn = *reinterpret_cast<const uint2*>(brow + (k + 1) * 2);
        }
        const __bf16* hb = &hbuf[k & 1][0];
#pragma unroll
        for (int jh = 0; jh < 2; ++jh) {
            int j0 = k * 64 + jh * 32;
            unsigned w = (jh ? wm.y : wm.x) >> (quad * 8);
            bf16x8 v0 = *reinterpret_cast<const bf16x8*>(hb + jh * 2048 + 0 * 512 + lane * 8);
            bf16x8 v1 = *reinterpret_cast<const bf16x8*>(hb + jh * 2048 + 1 * 512 + lane * 8);
            bf16x8 v2 = *reinterpret_cast<const bf16x8*>(hb + jh * 2048 + 2 * 512 + lane * 8);
            bf16x8 v3 = *reinterpret_cast<const bf16x8*>(hb + jh * 2048 + 3 * 512 + lane * 8);
            const float4* lp = reinterpret_cast<const float4*>(&lds_pq[j0 + quad * 8]);
            float4 q01 = lp[0], q23 = lp[1], q45 = lp[2], q67 = lp[3];
            float P[8] = {q01.x, q01.z, q23.x, q23.z, q45.x, q45.z, q67.x, q67.z};
            float Q[8] = {q01.y, q01.w, q23.y, q23.w, q45.y, q45.w, q67.y, q67.w};
            bf16x8 af;
#pragma unroll
            for (int t = 0; t < 8; ++t) {
                bool pos = P[t] > T;
                float p = (pos ? P[t] : Q[t]) * (pos ? A : C);
                af[t] = ((w >> t) & 1u) ? (__bf16)p : (__bf16)0.f;
            }
            acc0 = __builtin_amdgcn_mfma_f32_16x16x32_bf16(af, v0, acc0, 0, 0, 0);
            acc1 = __builtin_amdgcn_mfma_f32_16x16x32_bf16(af, v1, acc1, 0, 0, 0);
            acc2 = __builtin_amdgcn_mfma_f32_16x16x32_bf16(af, v2, acc2, 0, 0, 0);
            acc3 = __builtin_amdgcn_mfma_f32_16x16x32_bf16(af, v3, acc3, 0, 0, 0);
            acc4 = __builtin_amdgcn_mfma_f32_16x16x32_bf16(af, ones, acc4, 0, 0, 0);
        }
        if (more)
            *reinterpret_cast<bf16x8*>(&hbuf[(k + 1) & 1][tid * 8]) = st;
        wm = wmn;
        __syncthreads();
    }

    if (fr == 0) {
#pragma unroll
        for (int r = 0; r < 4; ++r)
            den[(jc * NROW + i0 + wave * 16 + quad * 4 + r) * NH + head] = acc4[r];
    }
#pragma unroll
    for (int r = 0; r < 4; ++r) {
        int orow = quad * 4 + r;
        int ob = (jc * NROW + i0 + wave * 16 + orow) * NF + head * ND + fr;
        num[ob +  0] = acc0[r];
        num[ob + 16] = acc1[r];
        num[ob + 32] = acc2[r];
        num[ob + 48] = acc3[r];
    }
}

// ---------------------------------------------------------------------------
// Kernel 4: out[i,c] = sum_jc num[jc][i][c] / sum_jc den[jc][i][c>>6]
// ---------------------------------------------------------------------------
__global__ __launch_bounds__(256) void k_reduce(const float* __restrict__ num,
                                                const float* __restrict__ den,
                                                float* __restrict__ out) {
    int idx = blockIdx.x * 256 + threadIdx.x;     // 0 .. NROW*NF
    int i = idx >> 9;
    int c = idx & 511;
    int head = c >> 6;
    float ns = num[i * NF + c] + num[(NROW + i) * NF + c]
             + num[(2 * NROW + i) * NF + c] + num[(3 * NROW + i) * NF + c];
    float ds = den[i * NH + head] + den[(NROW + i) * NH + head]
             + den[(2 * NROW + i) * NH + head] + den[(3 * NROW + i) * NH + head];
    out[idx] = ns / fmaxf(ds, 1e-30f);
}

// ---------------------------------------------------------------------------
extern "C" void kernel_launch(void* const* d_in, const int* in_sizes, int n_in,
                              void* d_out, int out_size, void* d_ws, size_t ws_size,
                              hipStream_t stream) {
    const float* x_raw  = (const float*)d_in[0];
    const int*   adj    = (const int*)d_in[1];
    const float* W_raw  = (const float*)d_in[2];
    const float* as_raw = (const float*)d_in[3];
    const float* ad_raw = (const float*)d_in[4];
    float* out = (float*)d_out;

    char* ws = (char*)d_ws;
    __bf16*   hT     = (__bf16*)(ws);                    // 3,145,728 B
    float*    e_srcT = (float*)(ws + 3145728);           //    98,304 B
    float*    e_dstT = (float*)(ws + 3244032);           //    98,304 B
    unsigned* maxkey = (unsigned*)(ws + 3342336);        //        64 B
    unsigned* bits   = (unsigned*)(ws + 3342400);        // 1,179,648 B
    __bf16*   xb     = (__bf16*)(ws + 4522048);          // 3,145,728 B
    __bf16*   Wb     = (__bf16*)(ws + 7667776);          //   524,288 B
    float*    num    = (float*)(ws + 8192064);           // 25,165,824 B
    float*    den    = (float*)(ws + 33357888);          //   393,216 B
    // total 33,751,104 B (<= previously-verified 35.7 MB capacity)

    k_prep<<<4864, 256, 0, stream>>>(x_raw, W_raw, adj, xb, Wb,
                                     (unsigned long long*)bits, maxkey);
    k_gemm<<<1536, 256, 0, stream>>>(xb, Wb, hT);
    k_edgesT<<<dim3(12, 8), 256, 0, stream>>>(hT, as_raw, ad_raw, e_srcT, e_dstT, maxkey);
    k_attn<4><<<24 * 4 * 8, 512, 0, stream>>>(bits, e_srcT, e_dstT, maxkey, hT, num, den);
    k_reduce<<<NROW * NF / 256, 256, 0, stream>>>(num, den, out);
}